// Round 3
// baseline (71.414 us; speedup 1.0000x reference)
//
#include <hip/hip_runtime.h>
#include <math.h>

#define BATCH 32
#define HW    (512*512)
#define N4    (HW/4)
#define BPB   64     // blocks per batch (2048 total -> 8 blocks/CU)
#define TPB   256

// workspace layout (bytes)
#define WS_SSUM   0      // double [B][12]
#define WS_DSUM   3072   // double [B][3]
#define WS_MU     3840   // float  [B][12]
#define WS_LCONST 5376   // float  [B]
#define WS_COUNTS 5504   // uint   [B][3]
#define WS_BYTES  5888

__device__ __forceinline__ float waveReduce(float v) {
#pragma unroll
  for (int off = 32; off > 0; off >>= 1) v += __shfl_down(v, off, 64);
  return v;
}

__device__ __forceinline__ void accum1(float x0, float x1, float x2, float x3, int l,
                                       float* s, float* c) {
  float m1 = (l == 1) ? 1.f : 0.f;
  float m2 = (l == 2) ? 1.f : 0.f;
  float m3 = (l == 3) ? 1.f : 0.f;
  c[0] += m1; c[1] += m2; c[2] += m3;
  s[0] += m1*x0; s[1]  += m1*x1; s[2]  += m1*x2; s[3]  += m1*x3;
  s[4] += m2*x0; s[5]  += m2*x1; s[6]  += m2*x2; s[7]  += m2*x3;
  s[8] += m3*x0; s[9]  += m3*x1; s[10] += m3*x2; s[11] += m3*x3;
}

// Pass 1: per-batch counts[1..3] and ssum[seg=1..3][4]
__global__ __launch_bounds__(TPB, 4) void k_sums(const float* __restrict__ emb,
                                                 const int*   __restrict__ lab,
                                                 double*      __restrict__ ssum,
                                                 unsigned int* __restrict__ counts) {
  const int b   = blockIdx.y;
  const int tid = threadIdx.x;
  const float4* e0 = (const float4*)emb + (size_t)(b*4 + 0) * N4;
  const float4* e1 = (const float4*)emb + (size_t)(b*4 + 1) * N4;
  const float4* e2 = (const float4*)emb + (size_t)(b*4 + 2) * N4;
  const float4* e3 = (const float4*)emb + (size_t)(b*4 + 3) * N4;
  const int4*   lp = (const int4*)lab + (size_t)b * N4;

  float s[12]; float c[3] = {0.f, 0.f, 0.f};
#pragma unroll
  for (int v = 0; v < 12; v++) s[v] = 0.f;

  const int stride = BPB * TPB;
  int i = blockIdx.x * TPB + tid;          // N4 / stride == 4 exactly
#pragma unroll
  for (int it = 0; it < 2; ++it) {
    int j = i + stride;
    float4 a0 = e0[i], a1 = e1[i], a2 = e2[i], a3 = e3[i]; int4 la = lp[i];
    float4 b0 = e0[j], b1 = e1[j], b2 = e2[j], b3 = e3[j]; int4 lb = lp[j];
    accum1(a0.x, a1.x, a2.x, a3.x, la.x, s, c);
    accum1(a0.y, a1.y, a2.y, a3.y, la.y, s, c);
    accum1(a0.z, a1.z, a2.z, a3.z, la.z, s, c);
    accum1(a0.w, a1.w, a2.w, a3.w, la.w, s, c);
    accum1(b0.x, b1.x, b2.x, b3.x, lb.x, s, c);
    accum1(b0.y, b1.y, b2.y, b3.y, lb.y, s, c);
    accum1(b0.z, b1.z, b2.z, b3.z, lb.z, s, c);
    accum1(b0.w, b1.w, b2.w, b3.w, lb.w, s, c);
    i += 2 * stride;
  }

  __shared__ float red[4][16];
  int wave = tid >> 6, lane = tid & 63;
  float vals[15];
#pragma unroll
  for (int v = 0; v < 12; v++) vals[v] = s[v];
#pragma unroll
  for (int k = 0; k < 3; k++) vals[12 + k] = c[k];
#pragma unroll
  for (int v = 0; v < 15; v++) {
    float r = waveReduce(vals[v]);
    if (lane == 0) red[wave][v] = r;
  }
  __syncthreads();
  if (tid < 15) {
    float t = red[0][tid] + red[1][tid] + red[2][tid] + red[3][tid];
    if (tid < 12) atomicAdd(&ssum[b*12 + tid], (double)t);
    else          atomicAdd(&counts[b*3 + (tid - 12)], (unsigned)(t + 0.5f));
  }
}

// Tiny: mu, distance term (exact masking semantics), reg term
__global__ void k_mu(const double* __restrict__ ssum, const unsigned* __restrict__ counts,
                     float* __restrict__ muout, float* __restrict__ lconst) {
  int b = threadIdx.x;
  if (b >= BATCH) return;
  float mu[4][4];
#pragma unroll
  for (int cc = 0; cc < 4; cc++) mu[0][cc] = 0.f;
#pragma unroll
  for (int s = 1; s < 4; s++) {
    unsigned cnt = counts[b*3 + (s-1)];
    double cs = (cnt > 0) ? (double)cnt : 1.0;
#pragma unroll
    for (int cc = 0; cc < 4; cc++) {
      float v = (float)(ssum[b*12 + (s-1)*4 + cc] / cs);
      mu[s][cc] = v;
      muout[b*12 + (s-1)*4 + cc] = v;
    }
  }
  float mnsum = 0.f; int msum = 0;
#pragma unroll
  for (int i = 0; i < 4; i++) {
#pragma unroll
    for (int j = 0; j < 4; j++) {
      float sabs = 0.f, nsq = 0.f;
#pragma unroll
      for (int cc = 0; cc < 4; cc++) {
        float bv = (mu[i][cc] != 0.f) ? mu[j][cc] : 0.f;
        float iv = (bv != 0.f) ? mu[i][cc] : 0.f;
        float df = bv - iv;
        sabs += fabsf(df);
        nsq  += df * df;
      }
      if (sabs != 0.f) {
        msum += 1;
        float t = fmaxf(6.0f - sqrtf(nsq), 0.f);
        mnsum += t * t;
      }
    }
  }
  float l_dist = (msum > 0) ? (mnsum / (float)msum) : 0.f;
  float rs = 0.f;
#pragma unroll
  for (int s = 0; s < 4; s++) {
    float nsq = 0.f;
#pragma unroll
    for (int cc = 0; cc < 4; cc++) nsq += mu[s][cc] * mu[s][cc];
    rs += sqrtf(nsq);
  }
  lconst[b] = l_dist + 0.001f * (rs * 0.25f);
}

__device__ __forceinline__ void var1(float x0, float x1, float x2, float x3, int l,
                                     const float* m1v, const float* m2v, const float* m3v,
                                     float& a1, float& a2, float& a3) {
  float m1 = (l == 1) ? 1.f : 0.f;
  float m2 = (l == 2) ? 1.f : 0.f;
  float m3 = (l == 3) ? 1.f : 0.f;
  float d0 = x0 - (m1*m1v[0] + m2*m2v[0] + m3*m3v[0]);
  float d1 = x1 - (m1*m1v[1] + m2*m2v[1] + m3*m3v[1]);
  float d2 = x2 - (m1*m1v[2] + m2*m2v[2] + m3*m3v[2]);
  float d3 = x3 - (m1*m1v[3] + m2*m2v[3] + m3*m3v[3]);
  float dsq = d0*d0 + d1*d1 + d2*d2 + d3*d3;
  float h = fmaxf(sqrtf(dsq) - 0.5f, 0.f);
  float hh = h * h;
  a1 += hh * m1; a2 += hh * m2; a3 += hh * m3;
}

// Pass 2: per-pixel hinge distance to own cluster mean
__global__ __launch_bounds__(TPB, 4) void k_var(const float* __restrict__ emb,
                                                const int*   __restrict__ lab,
                                                const float* __restrict__ mu,
                                                double*      __restrict__ dsum) {
  const int b   = blockIdx.y;
  const int tid = threadIdx.x;
  const float4* e0 = (const float4*)emb + (size_t)(b*4 + 0) * N4;
  const float4* e1 = (const float4*)emb + (size_t)(b*4 + 1) * N4;
  const float4* e2 = (const float4*)emb + (size_t)(b*4 + 2) * N4;
  const float4* e3 = (const float4*)emb + (size_t)(b*4 + 3) * N4;
  const int4*   lp = (const int4*)lab + (size_t)b * N4;

  float m1v[4], m2v[4], m3v[4];
#pragma unroll
  for (int cc = 0; cc < 4; cc++) {
    m1v[cc] = mu[b*12 + 0 + cc];
    m2v[cc] = mu[b*12 + 4 + cc];
    m3v[cc] = mu[b*12 + 8 + cc];
  }
  float a1 = 0.f, a2 = 0.f, a3 = 0.f;

  const int stride = BPB * TPB;
  int i = blockIdx.x * TPB + tid;
#pragma unroll
  for (int it = 0; it < 2; ++it) {
    int j = i + stride;
    float4 a0 = e0[i], a1f = e1[i], a2f = e2[i], a3f = e3[i]; int4 la = lp[i];
    float4 b0 = e0[j], b1f = e1[j], b2f = e2[j], b3f = e3[j]; int4 lb = lp[j];
    var1(a0.x, a1f.x, a2f.x, a3f.x, la.x, m1v, m2v, m3v, a1, a2, a3);
    var1(a0.y, a1f.y, a2f.y, a3f.y, la.y, m1v, m2v, m3v, a1, a2, a3);
    var1(a0.z, a1f.z, a2f.z, a3f.z, la.z, m1v, m2v, m3v, a1, a2, a3);
    var1(a0.w, a1f.w, a2f.w, a3f.w, la.w, m1v, m2v, m3v, a1, a2, a3);
    var1(b0.x, b1f.x, b2f.x, b3f.x, lb.x, m1v, m2v, m3v, a1, a2, a3);
    var1(b0.y, b1f.y, b2f.y, b3f.y, lb.y, m1v, m2v, m3v, a1, a2, a3);
    var1(b0.z, b1f.z, b2f.z, b3f.z, lb.z, m1v, m2v, m3v, a1, a2, a3);
    var1(b0.w, b1f.w, b2f.w, b3f.w, lb.w, m1v, m2v, m3v, a1, a2, a3);
    i += 2 * stride;
  }

  __shared__ float red[4][3];
  int wave = tid >> 6, lane = tid & 63;
  float vals[3] = {a1, a2, a3};
#pragma unroll
  for (int v = 0; v < 3; v++) {
    float r = waveReduce(vals[v]);
    if (lane == 0) red[wave][v] = r;
  }
  __syncthreads();
  if (tid < 3) {
    float t = red[0][tid] + red[1][tid] + red[2][tid] + red[3][tid];
    atomicAdd(&dsum[b*3 + tid], (double)t);
  }
}

// Final: l_var per batch, gate on npres, mean over batches
__global__ void k_final(const double* __restrict__ dsum, const unsigned* __restrict__ counts,
                        const float* __restrict__ lconst, float* __restrict__ out) {
  int tid = threadIdx.x;
  float loss = 0.f;
  if (tid < BATCH) {
    int npres = 0; float acc = 0.f;
#pragma unroll
    for (int s = 1; s < 4; s++) {
      unsigned cnt = counts[tid*3 + (s-1)];
      if (cnt > 0) { npres++; acc += (float)(dsum[tid*3 + (s-1)] / (double)cnt); }
    }
    float l_var = (npres > 0) ? acc / (float)npres : 0.f;
    loss = (npres > 0) ? (l_var + lconst[tid]) : 0.f;
  }
#pragma unroll
  for (int off = 32; off > 0; off >>= 1) loss += __shfl_down(loss, off, 64);
  if (tid == 0) out[0] = loss / (float)BATCH;
}

extern "C" void kernel_launch(void* const* d_in, const int* in_sizes, int n_in,
                              void* d_out, int out_size, void* d_ws, size_t ws_size,
                              hipStream_t stream) {
  const float* emb = (const float*)d_in[0];
  const int*   lab = (const int*)d_in[2];   // d_in[1] = y, unused by reference
  float* out = (float*)d_out;
  char* ws = (char*)d_ws;
  double*   ssum   = (double*)(ws + WS_SSUM);
  double*   dsum   = (double*)(ws + WS_DSUM);
  float*    mu     = (float*)(ws + WS_MU);
  float*    lconst = (float*)(ws + WS_LCONST);
  unsigned* counts = (unsigned*)(ws + WS_COUNTS);

  hipMemsetAsync(d_ws, 0, WS_BYTES, stream);

  dim3 grid(BPB, BATCH);
  k_sums<<<grid, TPB, 0, stream>>>(emb, lab, ssum, counts);
  k_mu  <<<1, 64, 0, stream>>>(ssum, counts, mu, lconst);
  k_var <<<grid, TPB, 0, stream>>>(emb, lab, mu, dsum);
  k_final<<<1, 64, 0, stream>>>(dsum, counts, lconst, out);
}